// Round 16
// baseline (290.824 us; speedup 1.0000x reference)
//
#include <hip/hip_runtime.h>

typedef unsigned short u16;
typedef __bf16 bfx8 __attribute__((ext_vector_type(8)));
typedef float f32x4 __attribute__((ext_vector_type(4)));

#define B_ 2
#define S_ 2048
#define D_ 2048
#define H_ 16
#define HD_ 128
#define SD_ 6144   // 3*D row stride of qkv

__device__ __forceinline__ u16 f2bf(float f) {
  union { float f; unsigned u; } v; v.f = f;
  unsigned r = v.u + 0x7fffu + ((v.u >> 16) & 1u);
  return (u16)(r >> 16);
}
__device__ __forceinline__ float bf2f(u16 b) {
  union { unsigned u; float f; } v; v.u = ((unsigned)b) << 16;
  return v.f;
}
__device__ __forceinline__ void gload_lds16(const void* g, void* l) {
  __builtin_amdgcn_global_load_lds((const __attribute__((address_space(1))) void*)g,
                                   (__attribute__((address_space(3))) void*)l, 16, 0, 0);
}

#define BAR() do { asm volatile("" ::: "memory"); __builtin_amdgcn_s_barrier(); \
                   asm volatile("" ::: "memory"); } while (0)
#define WAIT_VM4() asm volatile("s_waitcnt vmcnt(4)" ::: "memory")
#define WAIT_VM3() asm volatile("s_waitcnt vmcnt(3)" ::: "memory")
#define WAIT_VM0() asm volatile("s_waitcnt vmcnt(0)" ::: "memory")

// L2-supertile XCD swizzle (R9-verified: QKV FETCH 176->115 MB).
__device__ __forceinline__ void tile_coords(int BM, int BN, int& m0, int& n0) {
  int flat = blockIdx.x + gridDim.x * blockIdx.y;
  int xcd = flat & 7, li = flat >> 3;
  int MW = gridDim.y >> 3;
  int half = li >> 1, nn = li & 1;
  int mloc = half % MW, nw = half / MW;
  m0 = (xcd * MW + mloc) * BM;
  n0 = (nw * 2 + nn) * BN;
}

// ---------------- fp32 -> bf16 elementwise (vectorized) ----------------
__global__ __launch_bounds__(256) void cvt_kernel(const float* __restrict__ in,
                                                  u16* __restrict__ out, int n4) {
  int i = blockIdx.x * blockDim.x + threadIdx.x;
  int stride = gridDim.x * blockDim.x;
  for (int idx = i; idx < n4; idx += stride) {
    float4 v = ((const float4*)in)[idx];
    uint2 o;
    o.x = (unsigned)f2bf(v.x) | ((unsigned)f2bf(v.y) << 16);
    o.y = (unsigned)f2bf(v.z) | ((unsigned)f2bf(v.w) << 16);
    ((uint2*)out)[idx] = o;
  }
}

// ---------------- fp32 [R][C] -> bf16 [C][R] transpose-convert ----------------
__global__ __launch_bounds__(256) void transpose_cvt(const float* __restrict__ in,
                                                     u16* __restrict__ out,
                                                     int R, int C) {
  __shared__ float tile[32][33];
  int tx = threadIdx.x, ty = threadIdx.y;
  int c0 = blockIdx.x * 32, r0 = blockIdx.y * 32;
  for (int i = 0; i < 4; ++i)
    tile[ty + i * 8][tx] = in[(size_t)(r0 + ty + i * 8) * C + c0 + tx];
  __syncthreads();
  for (int i = 0; i < 4; ++i)
    out[(size_t)(c0 + ty + i * 8) * R + r0 + tx] = f2bf(tile[tx][ty + i * 8]);
}

// ---------------- V transpose: qkv[b,s,2D+h*HD+hd] -> vt[bh][hd][s] ----------------
__global__ __launch_bounds__(256) void transpose_v(const u16* __restrict__ qkv,
                                                   u16* __restrict__ vt) {
  __shared__ u16 tile[32][33];
  int tx = threadIdx.x, ty = threadIdx.y;
  int bh = blockIdx.z;
  int b = bh >> 4, h = bh & 15;
  int s0 = blockIdx.x * 32, d0 = blockIdx.y * 32;
  const u16* src = qkv + (size_t)b * S_ * SD_ + 2 * D_ + h * HD_;
  for (int i = 0; i < 4; ++i)
    tile[ty + i * 8][tx] = src[(size_t)(s0 + ty + i * 8) * SD_ + d0 + tx];
  __syncthreads();
  u16* dst = vt + (size_t)bh * HD_ * S_;
  for (int i = 0; i < 4; ++i)
    dst[(size_t)(d0 + ty + i * 8) * S_ + s0 + tx] = tile[tx][ty + i * 8];
}

// ---------------- 256x256 bf16 GEMM (R11 form: best measured QKV, 125us) ----------------
template<int OUT_BF16>
__global__ __launch_bounds__(512, 2) void gemm8p(const u16* __restrict__ A,
                                                 const u16* __restrict__ Bt,
                                                 const float* __restrict__ bias,
                                                 void* __restrict__ Cout,
                                                 int M, int N, int K) {
  __shared__ u16 lds[2][2][2][256 * 32];   // [op][buf][kh] 131072 B

  int t = threadIdx.x, l = t & 63, w = t >> 6;
  int lr = l & 15, lg = l >> 4;
  int wr = w >> 2, wc = w & 3;

  int m0, n0;
  tile_coords(256, 256, m0, n0);

  f32x4 acc[8][4];
#pragma unroll
  for (int i = 0; i < 8; ++i)
#pragma unroll
    for (int j = 0; j < 4; ++j)
#pragma unroll
      for (int r = 0; r < 4; ++r) acc[i][j][r] = 0.0f;

  int srow = t >> 2, sc = t & 3;
  const u16* As0 = A  + (size_t)(m0 + srow) * K + ((sc ^ ((srow >> 1) & 3)) * 8);
  const u16* Bs0 = Bt + (size_t)(n0 + srow) * K + ((sc ^ ((srow >> 1) & 3)) * 8);
  size_t hstep = (size_t)128 * K;

#define STG_A(BUF, KH, KOFF) do { \
    gload_lds16(As0 + (KOFF),         &lds[0][BUF][KH][t * 8]); \
    gload_lds16(As0 + hstep + (KOFF), &lds[0][BUF][KH][4096 + t * 8]); \
  } while (0)
#define STG_B(BUF, KH, KOFF) do { \
    gload_lds16(Bs0 + (KOFF),         &lds[1][BUF][KH][t * 8]); \
    gload_lds16(Bs0 + hstep + (KOFF), &lds[1][BUF][KH][4096 + t * 8]); \
  } while (0)

  int NT = K >> 6;
  int rsw = (lg ^ ((lr >> 1) & 3)) * 8;   // read-side swizzled chunk (elems)
  int arow = wr * 128 + lr;
  int brow = wc * 64 + lr;

  STG_A(0, 0, 0); STG_B(0, 0, 0); STG_A(0, 1, 32); STG_B(0, 1, 32);
  WAIT_VM4();
  BAR();

  for (int g = 0; g < NT; ++g) {
    int cb = g & 1, sb = cb ^ 1;
    int koff = (g + 1) * 64;
    bool stg = (g + 1 < NT);
    bfx8 a0[4], a1[4], bfr[4];

    // ---- phase alpha: kh0 ----
    if (stg) { STG_A(sb, 0, koff); STG_B(sb, 0, koff); }
#pragma unroll
    for (int i = 0; i < 4; ++i) {
      a0[i] = *(const bfx8*)&lds[0][cb][0][(arow + i * 16) * 32 + rsw];
      a1[i] = *(const bfx8*)&lds[0][cb][0][(arow + 64 + i * 16) * 32 + rsw];
    }
#pragma unroll
    for (int j = 0; j < 4; ++j)
      bfr[j] = *(const bfx8*)&lds[1][cb][0][(brow + j * 16) * 32 + rsw];
    __builtin_amdgcn_s_setprio(1);
#pragma unroll
    for (int i = 0; i < 4; ++i)
#pragma unroll
      for (int j = 0; j < 4; ++j) {
        acc[i][j]     = __builtin_amdgcn_mfma_f32_16x16x32_bf16(a0[i], bfr[j], acc[i][j], 0, 0, 0);
        acc[4 + i][j] = __builtin_amdgcn_mfma_f32_16x16x32_bf16(a1[i], bfr[j], acc[4 + i][j], 0, 0, 0);
      }
    __builtin_amdgcn_s_setprio(0);
    if (stg) WAIT_VM4(); else WAIT_VM0();   // cur-tile kh1 landed
    BAR();

    // ---- phase beta: kh1 ----
    if (stg) { STG_A(sb, 1, koff + 32); STG_B(sb, 1, koff + 32); }
#pragma unroll
    for (int i = 0; i < 4; ++i) {
      a0[i] = *(const bfx8*)&lds[0][cb][1][(arow + i * 16) * 32 + rsw];
      a1[i] = *(const bfx8*)&lds[0][cb][1][(arow + 64 + i * 16) * 32 + rsw];
    }
#pragma unroll
    for (int j = 0; j < 4; ++j)
      bfr[j] = *(const bfx8*)&lds[1][cb][1][(brow + j * 16) * 32 + rsw];
    __builtin_amdgcn_s_setprio(1);
#pragma unroll
    for (int i = 0; i < 4; ++i)
#pragma unroll
      for (int j = 0; j < 4; ++j) {
        acc[i][j]     = __builtin_amdgcn_mfma_f32_16x16x32_bf16(a0[i], bfr[j], acc[i][j], 0, 0, 0);
        acc[4 + i][j] = __builtin_amdgcn_mfma_f32_16x16x32_bf16(a1[i], bfr[j], acc[4 + i][j], 0, 0, 0);
      }
    __builtin_amdgcn_s_setprio(0);
    if (stg) WAIT_VM4(); else WAIT_VM0();   // next-tile kh0 landed
    BAR();
  }
#undef STG_A
#undef STG_B

  for (int i = 0; i < 8; ++i) {
    int row = m0 + wr * 128 + i * 16 + lg * 4;
    for (int j = 0; j < 4; ++j) {
      int col = n0 + wc * 64 + j * 16 + lr;
      float bz = bias[col];
      for (int r = 0; r < 4; ++r) {
        float v = acc[i][j][r] + bz;
        if (OUT_BF16)
          ((u16*)Cout)[(size_t)(row + r) * N + col] = f2bf(v);
        else
          ((float*)Cout)[(size_t)(row + r) * N + col] = v;
      }
    }
  }
}

// ---------------- 128x256 2-phase bf16 GEMM (R9 form: best measured total) ----------------
template<int OUT_BF16>
__global__ __launch_bounds__(512, 2) void gemm2p(const u16* __restrict__ A,
                                                 const u16* __restrict__ Bt,
                                                 const float* __restrict__ bias,
                                                 void* __restrict__ Cout,
                                                 int M, int N, int K) {
  __shared__ u16 ldsA[2][2][128 * 32];
  __shared__ u16 ldsB[2][2][256 * 32];

  int t = threadIdx.x, l = t & 63, w = t >> 6;
  int lr = l & 15, lg = l >> 4;
  int wr = w >> 2, wc = w & 3;

  int m0, n0;
  tile_coords(128, 256, m0, n0);

  f32x4 acc[4][4];
#pragma unroll
  for (int i = 0; i < 4; ++i)
#pragma unroll
    for (int j = 0; j < 4; ++j)
#pragma unroll
      for (int r = 0; r < 4; ++r) acc[i][j][r] = 0.0f;

  int srow = t >> 2, sc = t & 3;
  int csw = (sc ^ ((srow >> 1) & 3)) * 8;
  const u16* As0 = A  + (size_t)(m0 + srow) * K + csw;
  const u16* Bs0 = Bt + (size_t)(n0 + srow) * K + csw;
  size_t hstep = (size_t)128 * K;

#define STG_A(BUF, KH, KOFF) \
    gload_lds16(As0 + (KOFF), &ldsA[BUF][KH][t * 8])
#define STG_B(BUF, KH, KOFF) do { \
    gload_lds16(Bs0 + (KOFF),         &ldsB[BUF][KH][t * 8]); \
    gload_lds16(Bs0 + hstep + (KOFF), &ldsB[BUF][KH][4096 + t * 8]); \
  } while (0)

  int NT = K >> 6;
  int rsw = (lg ^ ((lr >> 1) & 3)) * 8;
  int arow = wr * 64 + lr;
  int brow = wc * 64 + lr;

  STG_A(0, 0, 0); STG_B(0, 0, 0); STG_A(0, 1, 32); STG_B(0, 1, 32);
  WAIT_VM3();
  BAR();

  for (int g = 0; g < NT; ++g) {
    int cb = g & 1, sb = cb ^ 1;
    int koff = (g + 1) * 64;
    bool stg = (g + 1 < NT);
    bfx8 af[4], bfr[4];

    // ---- phase 0 (kk=0): stage next kh0 ----
#pragma unroll
    for (int i = 0; i < 4; ++i)
      af[i] = *(const bfx8*)&ldsA[cb][0][(arow + i * 16) * 32 + rsw];
#pragma unroll
    for (int j = 0; j < 4; ++j)
      bfr[j] = *(const bfx8*)&ldsB[cb][0][(brow + j * 16) * 32 + rsw];
    if (stg) { STG_A(sb, 0, koff); STG_B(sb, 0, koff); }
    BAR();
    __builtin_amdgcn_s_setprio(1);
#pragma unroll
    for (int i = 0; i < 4; ++i)
#pragma unroll
      for (int j = 0; j < 4; ++j)
        acc[i][j] = __builtin_amdgcn_mfma_f32_16x16x32_bf16(af[i], bfr[j], acc[i][j], 0, 0, 0);
    __builtin_amdgcn_s_setprio(0);
    if (stg) WAIT_VM3(); else WAIT_VM0();
    BAR();

    // ---- phase 1 (kk=1): stage next kh1 ----
#pragma unroll
    for (int i = 0; i < 4; ++i)
      af[i] = *(const bfx8*)&ldsA[cb][1][(arow + i * 16) * 32 + rsw];
#pragma unroll
    for (int j = 0; j < 4; ++j)
      bfr[j] = *(const bfx8*)&ldsB[cb][1][(brow + j * 16) * 32 + rsw];
    if (stg) { STG_A(sb, 1, koff + 32); STG_B(sb, 1, koff + 32); }
    BAR();
    __builtin_amdgcn_s_setprio(1);
#pragma unroll
    for (int i = 0; i < 4; ++i)
#pragma unroll
      for (int j = 0; j < 4; ++j)
        acc[i][j] = __builtin_amdgcn_mfma_f32_16x16x32_bf16(af[i], bfr[j], acc[i][j], 0, 0, 0);
    __builtin_amdgcn_s_setprio(0);
    if (stg) WAIT_VM3();
    BAR();
  }
#undef STG_A
#undef STG_B

  for (int i = 0; i < 4; ++i) {
    int row = m0 + wr * 64 + i * 16 + lg * 4;
    for (int j = 0; j < 4; ++j) {
      int col = n0 + wc * 64 + j * 16 + lr;
      float bz = bias[col];
      for (int r = 0; r < 4; ++r) {
        float v = acc[i][j][r] + bz;
        if (OUT_BF16)
          ((u16*)Cout)[(size_t)(row + r) * N + col] = f2bf(v);
        else
          ((float*)Cout)[(size_t)(row + r) * N + col] = v;
      }
    }
  }
}

// ---------------- causal flash attention: 2 waves x 32 q-rows (halved LDS redundancy) ----
// 128 threads, w in {0,1}, each wave owns 32 rows as two 16-row m-halves (R4-verified
// math). Same staged K/V bytes now feed 64 MFMA/wave (was 32) -> per-CU LDS reads
// halve. 512 blocks (equal-work pair (31-p, p), 33 iters each), 72KB -> 2 blocks/CU
// with independent barrier groups (cross-block pipe overlap).
#define STAGE(BUF, KT) do {                                                        \
    int kc_ = ((t & 15) ^ ((t >> 4) & 7)) * 8;                                     \
    for (int i_ = 0; i_ < 8; ++i_)                                                 \
      gload_lds16(kbase + (size_t)((KT) * 64 + i_ * 8 + (t >> 4)) * SD_ + kc_,     \
                  &Klds[BUF][i_ * 1024 + t * 8]);                                  \
    int vc_ = (KT) * 64 + (((t & 7) ^ ((t >> 3) & 7)) * 8);                        \
    for (int i_ = 0; i_ < 8; ++i_)                                                 \
      gload_lds16(vbase + (size_t)(i_ * 16 + (t >> 3)) * S_ + vc_,                 \
                  &Vlds[BUF][i_ * 1024 + t * 8]);                                  \
  } while (0)

__global__ __launch_bounds__(128) void attn_kernel(const u16* __restrict__ qkv,
                                                   const u16* __restrict__ vt,
                                                   u16* __restrict__ ctx) {
  __shared__ u16 Klds[2][64 * 128];   // [key][hd], swizzled (16B chunk ^ row&7)
  __shared__ u16 Vlds[2][128 * 64];   // [hd][key], swizzled
  __shared__ u16 Plds[2][32 * 64];    // per-wave P [q][key], swizzled

  int t = threadIdx.x, l = t & 63, w = t >> 6;   // w in {0,1}
  int lr = l & 15, lg = l >> 4;
  int sw = lr & 7;
  int bid = blockIdx.x;
  int pr = bid >> 5, bh = bid & 31;
  int b = bh >> 4, h = bh & 15;
  const float scale = 0.08838834764831845f;  // 1/sqrt(128)

  const u16* kbase = qkv + (size_t)b * S_ * SD_ + D_ + h * HD_;
  const u16* vbase = vt + (size_t)bh * HD_ * S_;

  for (int sgi = 0; sgi < 2; ++sgi) {
    int qt = sgi ? pr : (31 - pr);    // 64-row q-tile index, long segment first
    int q0 = qt * 64;
    int wbase = q0 + w * 32;          // wave covers rows wbase..wbase+31
    int nt = qt + 1;

    // Q fragments, both m-halves, pre-scaled bf16
    bfx8 qf[2][4];
    for (int m = 0; m < 2; ++m) {
      const u16* qbase = qkv + (size_t)(b * S_ + wbase + m * 16) * SD_ + h * HD_;
      for (int kk = 0; kk < 4; ++kk) {
        const u16* src = qbase + (size_t)lr * SD_ + kk * 32 + lg * 8;
        union { uint4 u; u16 s[8]; bfx8 bv; } iv, ov;
        iv.u = *(const uint4*)src;
        for (int j = 0; j < 8; ++j) ov.s[j] = f2bf(bf2f(iv.s[j]) * scale);
        qf[m][kk] = ov.bv;
      }
    }

    f32x4 o[2][8];            // O[m][q=lg*4+r][hd=ht*16+lr]
    float mrun[2], lrun[2];   // per-lane row q = wbase + m*16 + lr
    for (int m = 0; m < 2; ++m) {
      for (int ht = 0; ht < 8; ++ht)
        for (int r = 0; r < 4; ++r) o[m][ht][r] = 0.0f;
      mrun[m] = -INFINITY; lrun[m] = 0.0f;
    }

    if (sgi) __syncthreads();
    STAGE(0, 0);

    for (int kt = 0; kt < nt; ++kt) {
      int cur = kt & 1;
      __syncthreads();
      if (kt + 1 < nt) STAGE(cur ^ 1, kt + 1);

      int kb0 = kt * 64;

      // ---- S^T = K Q^T : sacc[m][n][r] = S[q=lr][key=kb0+n*16+lg*4+r] ----
      f32x4 sacc[2][4];
      for (int m = 0; m < 2; ++m)
        for (int n = 0; n < 4; ++n)
          for (int r = 0; r < 4; ++r) sacc[m][n][r] = 0.0f;
      for (int n = 0; n < 4; ++n) {
        bfx8 kf[4];
        int krow = n * 16 + lr;
        for (int kk = 0; kk < 4; ++kk)
          kf[kk] = *(const bfx8*)&Klds[cur][krow * 128 + ((kk * 4 + lg) ^ sw) * 8];
        for (int m = 0; m < 2; ++m)
          for (int kk = 0; kk < 4; ++kk)
            sacc[m][n] = __builtin_amdgcn_mfma_f32_16x16x32_bf16(kf[kk], qf[m][kk], sacc[m][n], 0, 0, 0);
      }

      // ---- in-register online softmax, per m-half ----
      for (int m = 0; m < 2; ++m) {
        int base = wbase + m * 16;
        int q = base + lr;
        int row = m * 16 + lr;
        if (kb0 + 63 > base) {          // diagonal tile: causal mask
          for (int n = 0; n < 4; ++n)
            for (int r = 0; r < 4; ++r)
              if (kb0 + n * 16 + lg * 4 + r > q) sacc[m][n][r] = -INFINITY;
        }
        float tm = -INFINITY;
        for (int n = 0; n < 4; ++n) {
          float a = fmaxf(fmaxf(sacc[m][n][0], sacc[m][n][1]),
                          fmaxf(sacc[m][n][2], sacc[m][n][3]));
          tm = fmaxf(tm, a);
        }
        tm = fmaxf(tm, __shfl_xor(tm, 16, 64));
        tm = fmaxf(tm, __shfl_xor(tm, 32, 64));
        float mold = mrun[m];
        float mnew = fmaxf(mold, tm);
        if (__any((int)(mnew > mold))) {   // exact defer: skip rescale if no row grew
          float corr = __expf(mold - mnew);
          lrun[m] *= corr;
          mrun[m] = mnew;
          for (int r = 0; r < 4; ++r) {
            float c = __shfl(corr, lg * 4 + r, 16);
            for (int ht = 0; ht < 8; ++ht) o[m][ht][r] *= c;
          }
        }
        float mm = mrun[m];
        float psum = 0.0f;
        for (int n = 0; n < 4; ++n) {
          float p0 = __expf(sacc[m][n][0] - mm);
          float p1 = __expf(sacc[m][n][1] - mm);
          float p2 = __expf(sacc[m][n][2] - mm);
          float p3 = __expf(sacc[m][n][3] - mm);
          psum += (p0 + p1) + (p2 + p3);
          uint2 pk;
          pk.x = (unsigned)f2bf(p0) | ((unsigned)f2bf(p1) << 16);
          pk.y = (unsigned)f2bf(p2) | ((unsigned)f2bf(p3) << 16);
          *(uint2*)&Plds[w][row * 64 + ((n * 2 + (lg >> 1)) ^ sw) * 8 + (lg & 1) * 4] = pk;
        }
        psum += __shfl_xor(psum, 16, 64);
        psum += __shfl_xor(psum, 32, 64);
        lrun[m] += psum;
      }

      // ---- O += P V (vb shared across both m) ----
      for (int kk = 0; kk < 2; ++kk) {
        bfx8 pa0 = *(const bfx8*)&Plds[w][lr * 64 + ((kk * 4 + lg) ^ sw) * 8];
        bfx8 pa1 = *(const bfx8*)&Plds[w][(16 + lr) * 64 + ((kk * 4 + lg) ^ sw) * 8];
        for (int ht = 0; ht < 8; ++ht) {
          bfx8 vb = *(const bfx8*)&Vlds[cur][(ht * 16 + lr) * 64 + ((kk * 4 + lg) ^ sw) * 8];
          o[0][ht] = __builtin_amdgcn_mfma_f32_16x16x32_bf16(pa0, vb, o[0][ht], 0, 0, 0);
          o[1][ht] = __builtin_amdgcn_mfma_f32_16x16x32_bf16(pa1, vb, o[1][ht], 0, 0, 0);
        }
      }
    }

    // epilogue
    for (int m = 0; m < 2; ++m)
      for (int r = 0; r < 4; ++r) {
        float inv = 1.0f / __shfl(lrun[m], lg * 4 + r, 16);
        int qa = wbase + m * 16 + lg * 4 + r;
        u16* dst = ctx + (size_t)(b * S_ + qa) * D_ + h * HD_;
        for (int ht = 0; ht < 8; ++ht)
          dst[ht * 16 + lr] = f2bf(o[m][ht][r] * inv);
      }
  }
}

extern "C" void kernel_launch(void* const* d_in, const int* in_sizes, int n_in,
                              void* d_out, int out_size, void* d_ws, size_t ws_size,
                              hipStream_t stream) {
  const float* hs     = (const float*)d_in[0];
  const float* w_attn = (const float*)d_in[1];
  const float* b_attn = (const float*)d_in[2];
  const float* w_proj = (const float*)d_in[3];
  const float* b_proj = (const float*)d_in[4];

  u16* Xb     = (u16*)d_ws;            // [4096][2048]
  u16* Wqkvt  = Xb     + 8388608;      // [6144][2048]
  u16* Wprojt = Wqkvt  + 12582912;     // [2048][2048]
  u16* qkvb   = Wprojt + 4194304;      // [4096][6144]
  u16* Vt     = qkvb   + 25165824;     // [32][128][2048]
  u16* ctxb   = Vt     + 8388608;      // [4096][2048]

  cvt_kernel<<<2048, 256, 0, stream>>>(hs, Xb, (B_ * S_ * D_) / 4);
  transpose_cvt<<<dim3(192, 64), dim3(32, 8), 0, stream>>>(w_attn, Wqkvt, D_, 3 * D_);
  transpose_cvt<<<dim3(64, 64), dim3(32, 8), 0, stream>>>(w_proj, Wprojt, D_, D_);
  gemm8p<1><<<dim3(24, 16), 512, 0, stream>>>(Xb, Wqkvt, b_attn, qkvb, 4096, 6144, 2048);
  transpose_v<<<dim3(64, 4, 32), dim3(32, 8), 0, stream>>>(qkvb, Vt);
  attn_kernel<<<dim3(512), 128, 0, stream>>>(qkvb, Vt, ctxb);
  gemm2p<0><<<dim3(8, 32), 512, 0, stream>>>(ctxb, Wprojt, b_proj, d_out, 4096, 2048, 2048);
}

// Round 17
// 270.519 us; speedup vs baseline: 1.0751x; 1.0751x over previous
//
#include <hip/hip_runtime.h>

typedef unsigned short u16;
typedef __bf16 bfx8 __attribute__((ext_vector_type(8)));
typedef float f32x4 __attribute__((ext_vector_type(4)));

#define B_ 2
#define S_ 2048
#define D_ 2048
#define H_ 16
#define HD_ 128
#define SD_ 6144   // 3*D row stride of qkv

__device__ __forceinline__ u16 f2bf(float f) {
  union { float f; unsigned u; } v; v.f = f;
  unsigned r = v.u + 0x7fffu + ((v.u >> 16) & 1u);
  return (u16)(r >> 16);
}
__device__ __forceinline__ float bf2f(u16 b) {
  union { unsigned u; float f; } v; v.u = ((unsigned)b) << 16;
  return v.f;
}
__device__ __forceinline__ void gload_lds16(const void* g, void* l) {
  __builtin_amdgcn_global_load_lds((const __attribute__((address_space(1))) void*)g,
                                   (__attribute__((address_space(3))) void*)l, 16, 0, 0);
}

#define BAR() do { asm volatile("" ::: "memory"); __builtin_amdgcn_s_barrier(); \
                   asm volatile("" ::: "memory"); } while (0)
#define WAIT_VM4() asm volatile("s_waitcnt vmcnt(4)" ::: "memory")
#define WAIT_VM3() asm volatile("s_waitcnt vmcnt(3)" ::: "memory")
#define WAIT_VM0() asm volatile("s_waitcnt vmcnt(0)" ::: "memory")

// L2-supertile XCD swizzle (R9-verified: QKV FETCH 176->115 MB).
__device__ __forceinline__ void tile_coords(int BM, int BN, int& m0, int& n0) {
  int flat = blockIdx.x + gridDim.x * blockIdx.y;
  int xcd = flat & 7, li = flat >> 3;
  int MW = gridDim.y >> 3;
  int half = li >> 1, nn = li & 1;
  int mloc = half % MW, nw = half / MW;
  m0 = (xcd * MW + mloc) * BM;
  n0 = (nw * 2 + nn) * BN;
}

// ---------------- fp32 -> bf16 elementwise (vectorized) ----------------
__global__ __launch_bounds__(256) void cvt_kernel(const float* __restrict__ in,
                                                  u16* __restrict__ out, int n4) {
  int i = blockIdx.x * blockDim.x + threadIdx.x;
  int stride = gridDim.x * blockDim.x;
  for (int idx = i; idx < n4; idx += stride) {
    float4 v = ((const float4*)in)[idx];
    uint2 o;
    o.x = (unsigned)f2bf(v.x) | ((unsigned)f2bf(v.y) << 16);
    o.y = (unsigned)f2bf(v.z) | ((unsigned)f2bf(v.w) << 16);
    ((uint2*)out)[idx] = o;
  }
}

// ---------------- fp32 [R][C] -> bf16 [C][R] transpose-convert ----------------
__global__ __launch_bounds__(256) void transpose_cvt(const float* __restrict__ in,
                                                     u16* __restrict__ out,
                                                     int R, int C) {
  __shared__ float tile[32][33];
  int tx = threadIdx.x, ty = threadIdx.y;
  int c0 = blockIdx.x * 32, r0 = blockIdx.y * 32;
  for (int i = 0; i < 4; ++i)
    tile[ty + i * 8][tx] = in[(size_t)(r0 + ty + i * 8) * C + c0 + tx];
  __syncthreads();
  for (int i = 0; i < 4; ++i)
    out[(size_t)(c0 + ty + i * 8) * R + r0 + tx] = f2bf(tile[tx][ty + i * 8]);
}

// ---------------- V transpose: qkv[b,s,2D+h*HD+hd] -> vt[bh][hd][s] ----------------
__global__ __launch_bounds__(256) void transpose_v(const u16* __restrict__ qkv,
                                                   u16* __restrict__ vt) {
  __shared__ u16 tile[32][33];
  int tx = threadIdx.x, ty = threadIdx.y;
  int bh = blockIdx.z;
  int b = bh >> 4, h = bh & 15;
  int s0 = blockIdx.x * 32, d0 = blockIdx.y * 32;
  const u16* src = qkv + (size_t)b * S_ * SD_ + 2 * D_ + h * HD_;
  for (int i = 0; i < 4; ++i)
    tile[ty + i * 8][tx] = src[(size_t)(s0 + ty + i * 8) * SD_ + d0 + tx];
  __syncthreads();
  u16* dst = vt + (size_t)bh * HD_ * S_;
  for (int i = 0; i < 4; ++i)
    dst[(size_t)(d0 + ty + i * 8) * S_ + s0 + tx] = tile[tx][ty + i * 8];
}

// ---------------- 256x256 bf16 GEMM (R11 form: best measured QKV, 125us) ----------------
template<int OUT_BF16>
__global__ __launch_bounds__(512, 2) void gemm8p(const u16* __restrict__ A,
                                                 const u16* __restrict__ Bt,
                                                 const float* __restrict__ bias,
                                                 void* __restrict__ Cout,
                                                 int M, int N, int K) {
  __shared__ u16 lds[2][2][2][256 * 32];   // [op][buf][kh] 131072 B

  int t = threadIdx.x, l = t & 63, w = t >> 6;
  int lr = l & 15, lg = l >> 4;
  int wr = w >> 2, wc = w & 3;

  int m0, n0;
  tile_coords(256, 256, m0, n0);

  f32x4 acc[8][4];
#pragma unroll
  for (int i = 0; i < 8; ++i)
#pragma unroll
    for (int j = 0; j < 4; ++j)
#pragma unroll
      for (int r = 0; r < 4; ++r) acc[i][j][r] = 0.0f;

  int srow = t >> 2, sc = t & 3;
  const u16* As0 = A  + (size_t)(m0 + srow) * K + ((sc ^ ((srow >> 1) & 3)) * 8);
  const u16* Bs0 = Bt + (size_t)(n0 + srow) * K + ((sc ^ ((srow >> 1) & 3)) * 8);
  size_t hstep = (size_t)128 * K;

#define STG_A(BUF, KH, KOFF) do { \
    gload_lds16(As0 + (KOFF),         &lds[0][BUF][KH][t * 8]); \
    gload_lds16(As0 + hstep + (KOFF), &lds[0][BUF][KH][4096 + t * 8]); \
  } while (0)
#define STG_B(BUF, KH, KOFF) do { \
    gload_lds16(Bs0 + (KOFF),         &lds[1][BUF][KH][t * 8]); \
    gload_lds16(Bs0 + hstep + (KOFF), &lds[1][BUF][KH][4096 + t * 8]); \
  } while (0)

  int NT = K >> 6;
  int rsw = (lg ^ ((lr >> 1) & 3)) * 8;   // read-side swizzled chunk (elems)
  int arow = wr * 128 + lr;
  int brow = wc * 64 + lr;

  STG_A(0, 0, 0); STG_B(0, 0, 0); STG_A(0, 1, 32); STG_B(0, 1, 32);
  WAIT_VM4();
  BAR();

  for (int g = 0; g < NT; ++g) {
    int cb = g & 1, sb = cb ^ 1;
    int koff = (g + 1) * 64;
    bool stg = (g + 1 < NT);
    bfx8 a0[4], a1[4], bfr[4];

    // ---- phase alpha: kh0 ----
    if (stg) { STG_A(sb, 0, koff); STG_B(sb, 0, koff); }
#pragma unroll
    for (int i = 0; i < 4; ++i) {
      a0[i] = *(const bfx8*)&lds[0][cb][0][(arow + i * 16) * 32 + rsw];
      a1[i] = *(const bfx8*)&lds[0][cb][0][(arow + 64 + i * 16) * 32 + rsw];
    }
#pragma unroll
    for (int j = 0; j < 4; ++j)
      bfr[j] = *(const bfx8*)&lds[1][cb][0][(brow + j * 16) * 32 + rsw];
    __builtin_amdgcn_s_setprio(1);
#pragma unroll
    for (int i = 0; i < 4; ++i)
#pragma unroll
      for (int j = 0; j < 4; ++j) {
        acc[i][j]     = __builtin_amdgcn_mfma_f32_16x16x32_bf16(a0[i], bfr[j], acc[i][j], 0, 0, 0);
        acc[4 + i][j] = __builtin_amdgcn_mfma_f32_16x16x32_bf16(a1[i], bfr[j], acc[4 + i][j], 0, 0, 0);
      }
    __builtin_amdgcn_s_setprio(0);
    if (stg) WAIT_VM4(); else WAIT_VM0();   // cur-tile kh1 landed
    BAR();

    // ---- phase beta: kh1 ----
    if (stg) { STG_A(sb, 1, koff + 32); STG_B(sb, 1, koff + 32); }
#pragma unroll
    for (int i = 0; i < 4; ++i) {
      a0[i] = *(const bfx8*)&lds[0][cb][1][(arow + i * 16) * 32 + rsw];
      a1[i] = *(const bfx8*)&lds[0][cb][1][(arow + 64 + i * 16) * 32 + rsw];
    }
#pragma unroll
    for (int j = 0; j < 4; ++j)
      bfr[j] = *(const bfx8*)&lds[1][cb][1][(brow + j * 16) * 32 + rsw];
    __builtin_amdgcn_s_setprio(1);
#pragma unroll
    for (int i = 0; i < 4; ++i)
#pragma unroll
      for (int j = 0; j < 4; ++j) {
        acc[i][j]     = __builtin_amdgcn_mfma_f32_16x16x32_bf16(a0[i], bfr[j], acc[i][j], 0, 0, 0);
        acc[4 + i][j] = __builtin_amdgcn_mfma_f32_16x16x32_bf16(a1[i], bfr[j], acc[4 + i][j], 0, 0, 0);
      }
    __builtin_amdgcn_s_setprio(0);
    if (stg) WAIT_VM4(); else WAIT_VM0();   // next-tile kh0 landed
    BAR();
  }
#undef STG_A
#undef STG_B

  for (int i = 0; i < 8; ++i) {
    int row = m0 + wr * 128 + i * 16 + lg * 4;
    for (int j = 0; j < 4; ++j) {
      int col = n0 + wc * 64 + j * 16 + lr;
      float bz = bias[col];
      for (int r = 0; r < 4; ++r) {
        float v = acc[i][j][r] + bz;
        if (OUT_BF16)
          ((u16*)Cout)[(size_t)(row + r) * N + col] = f2bf(v);
        else
          ((float*)Cout)[(size_t)(row + r) * N + col] = v;
      }
    }
  }
}

// ---------------- 128x256 2-phase bf16 GEMM (R9 form: best measured total) ----------------
template<int OUT_BF16>
__global__ __launch_bounds__(512, 2) void gemm2p(const u16* __restrict__ A,
                                                 const u16* __restrict__ Bt,
                                                 const float* __restrict__ bias,
                                                 void* __restrict__ Cout,
                                                 int M, int N, int K) {
  __shared__ u16 ldsA[2][2][128 * 32];
  __shared__ u16 ldsB[2][2][256 * 32];

  int t = threadIdx.x, l = t & 63, w = t >> 6;
  int lr = l & 15, lg = l >> 4;
  int wr = w >> 2, wc = w & 3;

  int m0, n0;
  tile_coords(128, 256, m0, n0);

  f32x4 acc[4][4];
#pragma unroll
  for (int i = 0; i < 4; ++i)
#pragma unroll
    for (int j = 0; j < 4; ++j)
#pragma unroll
      for (int r = 0; r < 4; ++r) acc[i][j][r] = 0.0f;

  int srow = t >> 2, sc = t & 3;
  int csw = (sc ^ ((srow >> 1) & 3)) * 8;
  const u16* As0 = A  + (size_t)(m0 + srow) * K + csw;
  const u16* Bs0 = Bt + (size_t)(n0 + srow) * K + csw;
  size_t hstep = (size_t)128 * K;

#define STG_A(BUF, KH, KOFF) \
    gload_lds16(As0 + (KOFF), &ldsA[BUF][KH][t * 8])
#define STG_B(BUF, KH, KOFF) do { \
    gload_lds16(Bs0 + (KOFF),         &ldsB[BUF][KH][t * 8]); \
    gload_lds16(Bs0 + hstep + (KOFF), &ldsB[BUF][KH][4096 + t * 8]); \
  } while (0)

  int NT = K >> 6;
  int rsw = (lg ^ ((lr >> 1) & 3)) * 8;
  int arow = wr * 64 + lr;
  int brow = wc * 64 + lr;

  STG_A(0, 0, 0); STG_B(0, 0, 0); STG_A(0, 1, 32); STG_B(0, 1, 32);
  WAIT_VM3();
  BAR();

  for (int g = 0; g < NT; ++g) {
    int cb = g & 1, sb = cb ^ 1;
    int koff = (g + 1) * 64;
    bool stg = (g + 1 < NT);
    bfx8 af[4], bfr[4];

    // ---- phase 0 (kk=0): stage next kh0 ----
#pragma unroll
    for (int i = 0; i < 4; ++i)
      af[i] = *(const bfx8*)&ldsA[cb][0][(arow + i * 16) * 32 + rsw];
#pragma unroll
    for (int j = 0; j < 4; ++j)
      bfr[j] = *(const bfx8*)&ldsB[cb][0][(brow + j * 16) * 32 + rsw];
    if (stg) { STG_A(sb, 0, koff); STG_B(sb, 0, koff); }
    BAR();
    __builtin_amdgcn_s_setprio(1);
#pragma unroll
    for (int i = 0; i < 4; ++i)
#pragma unroll
      for (int j = 0; j < 4; ++j)
        acc[i][j] = __builtin_amdgcn_mfma_f32_16x16x32_bf16(af[i], bfr[j], acc[i][j], 0, 0, 0);
    __builtin_amdgcn_s_setprio(0);
    if (stg) WAIT_VM3(); else WAIT_VM0();
    BAR();

    // ---- phase 1 (kk=1): stage next kh1 ----
#pragma unroll
    for (int i = 0; i < 4; ++i)
      af[i] = *(const bfx8*)&ldsA[cb][1][(arow + i * 16) * 32 + rsw];
#pragma unroll
    for (int j = 0; j < 4; ++j)
      bfr[j] = *(const bfx8*)&ldsB[cb][1][(brow + j * 16) * 32 + rsw];
    if (stg) { STG_A(sb, 1, koff + 32); STG_B(sb, 1, koff + 32); }
    BAR();
    __builtin_amdgcn_s_setprio(1);
#pragma unroll
    for (int i = 0; i < 4; ++i)
#pragma unroll
      for (int j = 0; j < 4; ++j)
        acc[i][j] = __builtin_amdgcn_mfma_f32_16x16x32_bf16(af[i], bfr[j], acc[i][j], 0, 0, 0);
    __builtin_amdgcn_s_setprio(0);
    if (stg) WAIT_VM3();
    BAR();
  }
#undef STG_A
#undef STG_B

  for (int i = 0; i < 4; ++i) {
    int row = m0 + wr * 64 + i * 16 + lg * 4;
    for (int j = 0; j < 4; ++j) {
      int col = n0 + wc * 64 + j * 16 + lr;
      float bz = bias[col];
      for (int r = 0; r < 4; ++r) {
        float v = acc[i][j][r] + bz;
        if (OUT_BF16)
          ((u16*)Cout)[(size_t)(row + r) * N + col] = f2bf(v);
        else
          ((float*)Cout)[(size_t)(row + r) * N + col] = v;
      }
    }
  }
}

// ---------------- causal flash attention (equal-work paired blocks, no setprio) ----------------
#define STAGE(BUF, KT) do {                                                        \
    int kc_ = ((t & 15) ^ ((t >> 4) & 7)) * 8;                                     \
    for (int i_ = 0; i_ < 4; ++i_)                                                 \
      gload_lds16(kbase + (size_t)((KT) * 64 + i_ * 16 + (t >> 4)) * SD_ + kc_,    \
                  &Klds[BUF][i_ * 2048 + t * 8]);                                  \
    int vc_ = (KT) * 64 + (((t & 7) ^ ((t >> 3) & 7)) * 8);                        \
    for (int i_ = 0; i_ < 4; ++i_)                                                 \
      gload_lds16(vbase + (size_t)(i_ * 32 + (t >> 3)) * S_ + vc_,                 \
                  &Vlds[BUF][i_ * 2048 + t * 8]);                                  \
  } while (0)

__global__ __launch_bounds__(256) void attn_kernel(const u16* __restrict__ qkv,
                                                   const u16* __restrict__ vt,
                                                   u16* __restrict__ ctx) {
  __shared__ u16 Klds[2][64 * 128];   // [key][hd], swizzled (16B chunk ^ row&7)
  __shared__ u16 Vlds[2][128 * 64];   // [hd][key], swizzled
  __shared__ u16 Plds[4][16 * 64];    // per-wave P [q][key], swizzled

  int t = threadIdx.x, l = t & 63, w = t >> 6;
  int lr = l & 15, lg = l >> 4;
  int sw = lr & 7;
  int bid = blockIdx.x;
  int pr = bid >> 5, bh = bid & 31;
  int b = bh >> 4, h = bh & 15;
  const float scale = 0.08838834764831845f;  // 1/sqrt(128)

  const u16* kbase = qkv + (size_t)b * S_ * SD_ + D_ + h * HD_;
  const u16* vbase = vt + (size_t)bh * HD_ * S_;

  for (int sgi = 0; sgi < 2; ++sgi) {
    int qt = sgi ? pr : (31 - pr);    // 64-row q-tile index, long segment first
    int q0 = qt * 64;
    int wbase = q0 + w * 16;
    int nt = qt + 1;

    bfx8 qf[4];
    {
      const u16* qbase = qkv + (size_t)(b * S_ + wbase) * SD_ + h * HD_;
      for (int kk = 0; kk < 4; ++kk) {
        const u16* src = qbase + (size_t)lr * SD_ + kk * 32 + lg * 8;
        union { uint4 u; u16 s[8]; bfx8 bv; } iv, ov;
        iv.u = *(const uint4*)src;
        for (int j = 0; j < 8; ++j) ov.s[j] = f2bf(bf2f(iv.s[j]) * scale);
        qf[kk] = ov.bv;
      }
    }

    f32x4 o[8];             // O[q=lg*4+r][hd=ht*16+lr]
    float mrun = -INFINITY, lrun = 0.0f;   // per-lane row q = wbase + lr
    for (int ht = 0; ht < 8; ++ht)
      for (int r = 0; r < 4; ++r) o[ht][r] = 0.0f;

    if (sgi) __syncthreads();
    STAGE(0, 0);

    for (int kt = 0; kt < nt; ++kt) {
      int cur = kt & 1;
      __syncthreads();
      if (kt + 1 < nt) STAGE(cur ^ 1, kt + 1);

      int kb0 = kt * 64;

      f32x4 sacc[4];
      for (int n = 0; n < 4; ++n)
        for (int r = 0; r < 4; ++r) sacc[n][r] = 0.0f;
      for (int n = 0; n < 4; ++n) {
        bfx8 kf[4];
        int krow = n * 16 + lr;
        for (int kk = 0; kk < 4; ++kk)
          kf[kk] = *(const bfx8*)&Klds[cur][krow * 128 + ((kk * 4 + lg) ^ sw) * 8];
        for (int kk = 0; kk < 4; ++kk)
          sacc[n] = __builtin_amdgcn_mfma_f32_16x16x32_bf16(kf[kk], qf[kk], sacc[n], 0, 0, 0);
      }

      int q = wbase + lr;
      if (kb0 + 63 > wbase) {
        for (int n = 0; n < 4; ++n)
          for (int r = 0; r < 4; ++r)
            if (kb0 + n * 16 + lg * 4 + r > q) sacc[n][r] = -INFINITY;
      }
      float tm = -INFINITY;
      for (int n = 0; n < 4; ++n) {
        float a = fmaxf(fmaxf(sacc[n][0], sacc[n][1]),
                        fmaxf(sacc[n][2], sacc[n][3]));
        tm = fmaxf(tm, a);
      }
      tm = fmaxf(tm, __shfl_xor(tm, 16, 64));
      tm = fmaxf(tm, __shfl_xor(tm, 32, 64));
      float mold = mrun;
      float mnew = fmaxf(mold, tm);
      if (__any((int)(mnew > mold))) {
        float corr = __expf(mold - mnew);
        lrun *= corr;
        mrun = mnew;
        for (int r = 0; r < 4; ++r) {
          float c = __shfl(corr, lg * 4 + r, 16);
          for (int ht = 0; ht < 8; ++ht) o[ht][r] *= c;
        }
      }
      float mm = mrun;
      float psum = 0.0f;
      for (int n = 0; n < 4; ++n) {
        float p0 = __expf(sacc[n][0] - mm);
        float p1 = __expf(sacc[n][1] - mm);
        float p2 = __expf(sacc[n][2] - mm);
        float p3 = __expf(sacc[n][3] - mm);
        psum += (p0 + p1) + (p2 + p3);
        uint2 pk;
        pk.x = (unsigned)f2bf(p0) | ((unsigned)f2bf(p1) << 16);
        pk.y = (unsigned)f2bf(p2) | ((unsigned)f2bf(p3) << 16);
        *(uint2*)&Plds[w][lr * 64 + ((n * 2 + (lg >> 1)) ^ sw) * 8 + (lg & 1) * 4] = pk;
      }
      psum += __shfl_xor(psum, 16, 64);
      psum += __shfl_xor(psum, 32, 64);
      lrun += psum;

      for (int kk = 0; kk < 2; ++kk) {
        bfx8 pa = *(const bfx8*)&Plds[w][lr * 64 + ((kk * 4 + lg) ^ sw) * 8];
        for (int ht = 0; ht < 8; ++ht) {
          bfx8 vb = *(const bfx8*)&Vlds[cur][(ht * 16 + lr) * 64 + ((kk * 4 + lg) ^ sw) * 8];
          o[ht] = __builtin_amdgcn_mfma_f32_16x16x32_bf16(pa, vb, o[ht], 0, 0, 0);
        }
      }
    }

    for (int r = 0; r < 4; ++r) {
      float inv = 1.0f / __shfl(lrun, lg * 4 + r, 16);
      int qa = wbase + lg * 4 + r;
      u16* dst = ctx + (size_t)(b * S_ + qa) * D_ + h * HD_;
      for (int ht = 0; ht < 8; ++ht)
        dst[ht * 16 + lr] = f2bf(o[ht][r] * inv);
    }
  }
}

extern "C" void kernel_launch(void* const* d_in, const int* in_sizes, int n_in,
                              void* d_out, int out_size, void* d_ws, size_t ws_size,
                              hipStream_t stream) {
  const float* hs     = (const float*)d_in[0];
  const float* w_attn = (const float*)d_in[1];
  const float* b_attn = (const float*)d_in[2];
  const float* w_proj = (const float*)d_in[3];
  const float* b_proj = (const float*)d_in[4];

  u16* Xb     = (u16*)d_ws;            // [4096][2048]
  u16* Wqkvt  = Xb     + 8388608;      // [6144][2048]
  u16* Wprojt = Wqkvt  + 12582912;     // [2048][2048]
  u16* qkvb   = Wprojt + 4194304;      // [4096][6144]
  u16* Vt     = qkvb   + 25165824;     // [32][128][2048]
  u16* ctxb   = Vt     + 8388608;      // [4096][2048]

  cvt_kernel<<<2048, 256, 0, stream>>>(hs, Xb, (B_ * S_ * D_) / 4);
  transpose_cvt<<<dim3(192, 64), dim3(32, 8), 0, stream>>>(w_attn, Wqkvt, D_, 3 * D_);
  transpose_cvt<<<dim3(64, 64), dim3(32, 8), 0, stream>>>(w_proj, Wprojt, D_, D_);
  gemm8p<1><<<dim3(24, 16), 512, 0, stream>>>(Xb, Wqkvt, b_attn, qkvb, 4096, 6144, 2048);
  transpose_v<<<dim3(64, 4, 32), dim3(32, 8), 0, stream>>>(qkvb, Vt);
  attn_kernel<<<dim3(512), 256, 0, stream>>>(qkvb, Vt, ctxb);
  gemm2p<0><<<dim3(8, 32), 512, 0, stream>>>(ctxb, Wprojt, b_proj, d_out, 4096, 2048, 2048);
}

// Round 18
// 266.593 us; speedup vs baseline: 1.0909x; 1.0147x over previous
//
#include <hip/hip_runtime.h>

typedef unsigned short u16;
typedef __bf16 bfx8 __attribute__((ext_vector_type(8)));
typedef float f32x4 __attribute__((ext_vector_type(4)));

#define B_ 2
#define S_ 2048
#define D_ 2048
#define H_ 16
#define HD_ 128
#define SD_ 6144   // 3*D row stride of qkv

__device__ __forceinline__ u16 f2bf(float f) {
  union { float f; unsigned u; } v; v.f = f;
  unsigned r = v.u + 0x7fffu + ((v.u >> 16) & 1u);
  return (u16)(r >> 16);
}
__device__ __forceinline__ float bf2f(u16 b) {
  union { unsigned u; float f; } v; v.u = ((unsigned)b) << 16;
  return v.f;
}
__device__ __forceinline__ void gload_lds16(const void* g, void* l) {
  __builtin_amdgcn_global_load_lds((const __attribute__((address_space(1))) void*)g,
                                   (__attribute__((address_space(3))) void*)l, 16, 0, 0);
}

#define BAR() do { asm volatile("" ::: "memory"); __builtin_amdgcn_s_barrier(); \
                   asm volatile("" ::: "memory"); } while (0)
#define WAIT_VM4() asm volatile("s_waitcnt vmcnt(4)" ::: "memory")
#define WAIT_VM3() asm volatile("s_waitcnt vmcnt(3)" ::: "memory")
#define WAIT_VM0() asm volatile("s_waitcnt vmcnt(0)" ::: "memory")

// L2-supertile XCD swizzle (R9-verified: QKV FETCH 176->115 MB).
__device__ __forceinline__ void tile_coords(int BM, int BN, int& m0, int& n0) {
  int flat = blockIdx.x + gridDim.x * blockIdx.y;
  int xcd = flat & 7, li = flat >> 3;
  int MW = gridDim.y >> 3;
  int half = li >> 1, nn = li & 1;
  int mloc = half % MW, nw = half / MW;
  m0 = (xcd * MW + mloc) * BM;
  n0 = (nw * 2 + nn) * BN;
}

// ---------------- fp32 -> bf16 elementwise (vectorized) ----------------
__global__ __launch_bounds__(256) void cvt_kernel(const float* __restrict__ in,
                                                  u16* __restrict__ out, int n4) {
  int i = blockIdx.x * blockDim.x + threadIdx.x;
  int stride = gridDim.x * blockDim.x;
  for (int idx = i; idx < n4; idx += stride) {
    float4 v = ((const float4*)in)[idx];
    uint2 o;
    o.x = (unsigned)f2bf(v.x) | ((unsigned)f2bf(v.y) << 16);
    o.y = (unsigned)f2bf(v.z) | ((unsigned)f2bf(v.w) << 16);
    ((uint2*)out)[idx] = o;
  }
}

// ------- fp32 [R][C] -> bf16 [C][R] transpose-convert, 64x64 tiles, vector I/O -------
// Lane handles 2 consecutive elems: float2 loads (256B/wave-row), packed uint
// bf16x2 stores (128B/wave-row). LDS stride 65 -> transposed read is lane-stride-2
// = 2-way bank aliasing = free (m136).
__global__ __launch_bounds__(256) void transpose_cvt64(const float* __restrict__ in,
                                                       u16* __restrict__ out,
                                                       int R, int C) {
  __shared__ float tile[64][65];
  int tx = threadIdx.x, ty = threadIdx.y;   // (32, 8)
  int c0 = blockIdx.x * 64, r0 = blockIdx.y * 64;
#pragma unroll
  for (int j = 0; j < 8; ++j) {
    int row = ty + j * 8;
    float2 v = *(const float2*)&in[(size_t)(r0 + row) * C + c0 + tx * 2];
    tile[row][tx * 2]     = v.x;
    tile[row][tx * 2 + 1] = v.y;
  }
  __syncthreads();
#pragma unroll
  for (int j = 0; j < 8; ++j) {
    int orow = ty + j * 8;                  // output row = original col c0+orow
    unsigned pk = (unsigned)f2bf(tile[tx * 2][orow]) |
                  ((unsigned)f2bf(tile[tx * 2 + 1][orow]) << 16);
    *(unsigned*)&out[(size_t)(c0 + orow) * R + r0 + tx * 2] = pk;
  }
}

// ---- V transpose: qkv[b,s,2D+h*HD+hd] -> vt[bh][hd][s], 64x64 tiles, vector I/O ----
__global__ __launch_bounds__(256) void transpose_v64(const u16* __restrict__ qkv,
                                                     u16* __restrict__ vt) {
  __shared__ u16 tile[64][66];              // stride 66 u16 -> dword lane-stride 2 (free)
  int tx = threadIdx.x, ty = threadIdx.y;   // (32, 8)
  int bh = blockIdx.z;
  int b = bh >> 4, h = bh & 15;
  int s0 = blockIdx.x * 64, d0 = blockIdx.y * 64;
  const u16* src = qkv + (size_t)b * S_ * SD_ + 2 * D_ + h * HD_;
#pragma unroll
  for (int j = 0; j < 8; ++j) {
    int row = ty + j * 8;                   // s-offset
    *(unsigned*)&tile[row][tx * 2] =
        *(const unsigned*)&src[(size_t)(s0 + row) * SD_ + d0 + tx * 2];
  }
  __syncthreads();
  u16* dst = vt + (size_t)bh * HD_ * S_;
#pragma unroll
  for (int j = 0; j < 8; ++j) {
    int orow = ty + j * 8;                  // hd-offset
    unsigned pk = (unsigned)tile[tx * 2][orow] |
                  ((unsigned)tile[tx * 2 + 1][orow] << 16);
    *(unsigned*)&dst[(size_t)(d0 + orow) * S_ + s0 + tx * 2] = pk;
  }
}

// ---------------- 256x256 bf16 GEMM (R11 form: best measured QKV, 125us) ----------------
template<int OUT_BF16>
__global__ __launch_bounds__(512, 2) void gemm8p(const u16* __restrict__ A,
                                                 const u16* __restrict__ Bt,
                                                 const float* __restrict__ bias,
                                                 void* __restrict__ Cout,
                                                 int M, int N, int K) {
  __shared__ u16 lds[2][2][2][256 * 32];   // [op][buf][kh] 131072 B

  int t = threadIdx.x, l = t & 63, w = t >> 6;
  int lr = l & 15, lg = l >> 4;
  int wr = w >> 2, wc = w & 3;

  int m0, n0;
  tile_coords(256, 256, m0, n0);

  f32x4 acc[8][4];
#pragma unroll
  for (int i = 0; i < 8; ++i)
#pragma unroll
    for (int j = 0; j < 4; ++j)
#pragma unroll
      for (int r = 0; r < 4; ++r) acc[i][j][r] = 0.0f;

  int srow = t >> 2, sc = t & 3;
  const u16* As0 = A  + (size_t)(m0 + srow) * K + ((sc ^ ((srow >> 1) & 3)) * 8);
  const u16* Bs0 = Bt + (size_t)(n0 + srow) * K + ((sc ^ ((srow >> 1) & 3)) * 8);
  size_t hstep = (size_t)128 * K;

#define STG_A(BUF, KH, KOFF) do { \
    gload_lds16(As0 + (KOFF),         &lds[0][BUF][KH][t * 8]); \
    gload_lds16(As0 + hstep + (KOFF), &lds[0][BUF][KH][4096 + t * 8]); \
  } while (0)
#define STG_B(BUF, KH, KOFF) do { \
    gload_lds16(Bs0 + (KOFF),         &lds[1][BUF][KH][t * 8]); \
    gload_lds16(Bs0 + hstep + (KOFF), &lds[1][BUF][KH][4096 + t * 8]); \
  } while (0)

  int NT = K >> 6;
  int rsw = (lg ^ ((lr >> 1) & 3)) * 8;   // read-side swizzled chunk (elems)
  int arow = wr * 128 + lr;
  int brow = wc * 64 + lr;

  STG_A(0, 0, 0); STG_B(0, 0, 0); STG_A(0, 1, 32); STG_B(0, 1, 32);
  WAIT_VM4();
  BAR();

  for (int g = 0; g < NT; ++g) {
    int cb = g & 1, sb = cb ^ 1;
    int koff = (g + 1) * 64;
    bool stg = (g + 1 < NT);
    bfx8 a0[4], a1[4], bfr[4];

    // ---- phase alpha: kh0 ----
    if (stg) { STG_A(sb, 0, koff); STG_B(sb, 0, koff); }
#pragma unroll
    for (int i = 0; i < 4; ++i) {
      a0[i] = *(const bfx8*)&lds[0][cb][0][(arow + i * 16) * 32 + rsw];
      a1[i] = *(const bfx8*)&lds[0][cb][0][(arow + 64 + i * 16) * 32 + rsw];
    }
#pragma unroll
    for (int j = 0; j < 4; ++j)
      bfr[j] = *(const bfx8*)&lds[1][cb][0][(brow + j * 16) * 32 + rsw];
    __builtin_amdgcn_s_setprio(1);
#pragma unroll
    for (int i = 0; i < 4; ++i)
#pragma unroll
      for (int j = 0; j < 4; ++j) {
        acc[i][j]     = __builtin_amdgcn_mfma_f32_16x16x32_bf16(a0[i], bfr[j], acc[i][j], 0, 0, 0);
        acc[4 + i][j] = __builtin_amdgcn_mfma_f32_16x16x32_bf16(a1[i], bfr[j], acc[4 + i][j], 0, 0, 0);
      }
    __builtin_amdgcn_s_setprio(0);
    if (stg) WAIT_VM4(); else WAIT_VM0();   // cur-tile kh1 landed
    BAR();

    // ---- phase beta: kh1 ----
    if (stg) { STG_A(sb, 1, koff + 32); STG_B(sb, 1, koff + 32); }
#pragma unroll
    for (int i = 0; i < 4; ++i) {
      a0[i] = *(const bfx8*)&lds[0][cb][1][(arow + i * 16) * 32 + rsw];
      a1[i] = *(const bfx8*)&lds[0][cb][1][(arow + 64 + i * 16) * 32 + rsw];
    }
#pragma unroll
    for (int j = 0; j < 4; ++j)
      bfr[j] = *(const bfx8*)&lds[1][cb][1][(brow + j * 16) * 32 + rsw];
    __builtin_amdgcn_s_setprio(1);
#pragma unroll
    for (int i = 0; i < 4; ++i)
#pragma unroll
      for (int j = 0; j < 4; ++j) {
        acc[i][j]     = __builtin_amdgcn_mfma_f32_16x16x32_bf16(a0[i], bfr[j], acc[i][j], 0, 0, 0);
        acc[4 + i][j] = __builtin_amdgcn_mfma_f32_16x16x32_bf16(a1[i], bfr[j], acc[4 + i][j], 0, 0, 0);
      }
    __builtin_amdgcn_s_setprio(0);
    if (stg) WAIT_VM4(); else WAIT_VM0();   // next-tile kh0 landed
    BAR();
  }
#undef STG_A
#undef STG_B

  for (int i = 0; i < 8; ++i) {
    int row = m0 + wr * 128 + i * 16 + lg * 4;
    for (int j = 0; j < 4; ++j) {
      int col = n0 + wc * 64 + j * 16 + lr;
      float bz = bias[col];
      for (int r = 0; r < 4; ++r) {
        float v = acc[i][j][r] + bz;
        if (OUT_BF16)
          ((u16*)Cout)[(size_t)(row + r) * N + col] = f2bf(v);
        else
          ((float*)Cout)[(size_t)(row + r) * N + col] = v;
      }
    }
  }
}

// ---------------- 128x256 2-phase bf16 GEMM (R9 form: best measured total) ----------------
template<int OUT_BF16>
__global__ __launch_bounds__(512, 2) void gemm2p(const u16* __restrict__ A,
                                                 const u16* __restrict__ Bt,
                                                 const float* __restrict__ bias,
                                                 void* __restrict__ Cout,
                                                 int M, int N, int K) {
  __shared__ u16 ldsA[2][2][128 * 32];
  __shared__ u16 ldsB[2][2][256 * 32];

  int t = threadIdx.x, l = t & 63, w = t >> 6;
  int lr = l & 15, lg = l >> 4;
  int wr = w >> 2, wc = w & 3;

  int m0, n0;
  tile_coords(128, 256, m0, n0);

  f32x4 acc[4][4];
#pragma unroll
  for (int i = 0; i < 4; ++i)
#pragma unroll
    for (int j = 0; j < 4; ++j)
#pragma unroll
      for (int r = 0; r < 4; ++r) acc[i][j][r] = 0.0f;

  int srow = t >> 2, sc = t & 3;
  int csw = (sc ^ ((srow >> 1) & 3)) * 8;
  const u16* As0 = A  + (size_t)(m0 + srow) * K + csw;
  const u16* Bs0 = Bt + (size_t)(n0 + srow) * K + csw;
  size_t hstep = (size_t)128 * K;

#define STG_A(BUF, KH, KOFF) \
    gload_lds16(As0 + (KOFF), &ldsA[BUF][KH][t * 8])
#define STG_B(BUF, KH, KOFF) do { \
    gload_lds16(Bs0 + (KOFF),         &ldsB[BUF][KH][t * 8]); \
    gload_lds16(Bs0 + hstep + (KOFF), &ldsB[BUF][KH][4096 + t * 8]); \
  } while (0)

  int NT = K >> 6;
  int rsw = (lg ^ ((lr >> 1) & 3)) * 8;
  int arow = wr * 64 + lr;
  int brow = wc * 64 + lr;

  STG_A(0, 0, 0); STG_B(0, 0, 0); STG_A(0, 1, 32); STG_B(0, 1, 32);
  WAIT_VM3();
  BAR();

  for (int g = 0; g < NT; ++g) {
    int cb = g & 1, sb = cb ^ 1;
    int koff = (g + 1) * 64;
    bool stg = (g + 1 < NT);
    bfx8 af[4], bfr[4];

    // ---- phase 0 (kk=0): stage next kh0 ----
#pragma unroll
    for (int i = 0; i < 4; ++i)
      af[i] = *(const bfx8*)&ldsA[cb][0][(arow + i * 16) * 32 + rsw];
#pragma unroll
    for (int j = 0; j < 4; ++j)
      bfr[j] = *(const bfx8*)&ldsB[cb][0][(brow + j * 16) * 32 + rsw];
    if (stg) { STG_A(sb, 0, koff); STG_B(sb, 0, koff); }
    BAR();
    __builtin_amdgcn_s_setprio(1);
#pragma unroll
    for (int i = 0; i < 4; ++i)
#pragma unroll
      for (int j = 0; j < 4; ++j)
        acc[i][j] = __builtin_amdgcn_mfma_f32_16x16x32_bf16(af[i], bfr[j], acc[i][j], 0, 0, 0);
    __builtin_amdgcn_s_setprio(0);
    if (stg) WAIT_VM3(); else WAIT_VM0();
    BAR();

    // ---- phase 1 (kk=1): stage next kh1 ----
#pragma unroll
    for (int i = 0; i < 4; ++i)
      af[i] = *(const bfx8*)&ldsA[cb][1][(arow + i * 16) * 32 + rsw];
#pragma unroll
    for (int j = 0; j < 4; ++j)
      bfr[j] = *(const bfx8*)&ldsB[cb][1][(brow + j * 16) * 32 + rsw];
    if (stg) { STG_A(sb, 1, koff + 32); STG_B(sb, 1, koff + 32); }
    BAR();
    __builtin_amdgcn_s_setprio(1);
#pragma unroll
    for (int i = 0; i < 4; ++i)
#pragma unroll
      for (int j = 0; j < 4; ++j)
        acc[i][j] = __builtin_amdgcn_mfma_f32_16x16x32_bf16(af[i], bfr[j], acc[i][j], 0, 0, 0);
    __builtin_amdgcn_s_setprio(0);
    if (stg) WAIT_VM3();
    BAR();
  }
#undef STG_A
#undef STG_B

  for (int i = 0; i < 4; ++i) {
    int row = m0 + wr * 64 + i * 16 + lg * 4;
    for (int j = 0; j < 4; ++j) {
      int col = n0 + wc * 64 + j * 16 + lr;
      float bz = bias[col];
      for (int r = 0; r < 4; ++r) {
        float v = acc[i][j][r] + bz;
        if (OUT_BF16)
          ((u16*)Cout)[(size_t)(row + r) * N + col] = f2bf(v);
        else
          ((float*)Cout)[(size_t)(row + r) * N + col] = v;
      }
    }
  }
}

// ---------------- causal flash attention (equal-work paired blocks, no setprio) ----------------
#define STAGE(BUF, KT) do {                                                        \
    int kc_ = ((t & 15) ^ ((t >> 4) & 7)) * 8;                                     \
    for (int i_ = 0; i_ < 4; ++i_)                                                 \
      gload_lds16(kbase + (size_t)((KT) * 64 + i_ * 16 + (t >> 4)) * SD_ + kc_,    \
                  &Klds[BUF][i_ * 2048 + t * 8]);                                  \
    int vc_ = (KT) * 64 + (((t & 7) ^ ((t >> 3) & 7)) * 8);                        \
    for (int i_ = 0; i_ < 4; ++i_)                                                 \
      gload_lds16(vbase + (size_t)(i_ * 32 + (t >> 3)) * S_ + vc_,                 \
                  &Vlds[BUF][i_ * 2048 + t * 8]);                                  \
  } while (0)

__global__ __launch_bounds__(256) void attn_kernel(const u16* __restrict__ qkv,
                                                   const u16* __restrict__ vt,
                                                   u16* __restrict__ ctx) {
  __shared__ u16 Klds[2][64 * 128];   // [key][hd], swizzled (16B chunk ^ row&7)
  __shared__ u16 Vlds[2][128 * 64];   // [hd][key], swizzled
  __shared__ u16 Plds[4][16 * 64];    // per-wave P [q][key], swizzled

  int t = threadIdx.x, l = t & 63, w = t >> 6;
  int lr = l & 15, lg = l >> 4;
  int sw = lr & 7;
  int bid = blockIdx.x;
  int pr = bid >> 5, bh = bid & 31;
  int b = bh >> 4, h = bh & 15;
  const float scale = 0.08838834764831845f;  // 1/sqrt(128)

  const u16* kbase = qkv + (size_t)b * S_ * SD_ + D_ + h * HD_;
  const u16* vbase = vt + (size_t)bh * HD_ * S_;

  for (int sgi = 0; sgi < 2; ++sgi) {
    int qt = sgi ? pr : (31 - pr);    // 64-row q-tile index, long segment first
    int q0 = qt * 64;
    int wbase = q0 + w * 16;
    int nt = qt + 1;

    bfx8 qf[4];
    {
      const u16* qbase = qkv + (size_t)(b * S_ + wbase) * SD_ + h * HD_;
      for (int kk = 0; kk < 4; ++kk) {
        const u16* src = qbase + (size_t)lr * SD_ + kk * 32 + lg * 8;
        union { uint4 u; u16 s[8]; bfx8 bv; } iv, ov;
        iv.u = *(const uint4*)src;
        for (int j = 0; j < 8; ++j) ov.s[j] = f2bf(bf2f(iv.s[j]) * scale);
        qf[kk] = ov.bv;
      }
    }

    f32x4 o[8];             // O[q=lg*4+r][hd=ht*16+lr]
    float mrun = -INFINITY, lrun = 0.0f;   // per-lane row q = wbase + lr
    for (int ht = 0; ht < 8; ++ht)
      for (int r = 0; r < 4; ++r) o[ht][r] = 0.0f;

    if (sgi) __syncthreads();
    STAGE(0, 0);

    for (int kt = 0; kt < nt; ++kt) {
      int cur = kt & 1;
      __syncthreads();
      if (kt + 1 < nt) STAGE(cur ^ 1, kt + 1);

      int kb0 = kt * 64;

      f32x4 sacc[4];
      for (int n = 0; n < 4; ++n)
        for (int r = 0; r < 4; ++r) sacc[n][r] = 0.0f;
      for (int n = 0; n < 4; ++n) {
        bfx8 kf[4];
        int krow = n * 16 + lr;
        for (int kk = 0; kk < 4; ++kk)
          kf[kk] = *(const bfx8*)&Klds[cur][krow * 128 + ((kk * 4 + lg) ^ sw) * 8];
        for (int kk = 0; kk < 4; ++kk)
          sacc[n] = __builtin_amdgcn_mfma_f32_16x16x32_bf16(kf[kk], qf[kk], sacc[n], 0, 0, 0);
      }

      int q = wbase + lr;
      if (kb0 + 63 > wbase) {
        for (int n = 0; n < 4; ++n)
          for (int r = 0; r < 4; ++r)
            if (kb0 + n * 16 + lg * 4 + r > q) sacc[n][r] = -INFINITY;
      }
      float tm = -INFINITY;
      for (int n = 0; n < 4; ++n) {
        float a = fmaxf(fmaxf(sacc[n][0], sacc[n][1]),
                        fmaxf(sacc[n][2], sacc[n][3]));
        tm = fmaxf(tm, a);
      }
      tm = fmaxf(tm, __shfl_xor(tm, 16, 64));
      tm = fmaxf(tm, __shfl_xor(tm, 32, 64));
      float mold = mrun;
      float mnew = fmaxf(mold, tm);
      if (__any((int)(mnew > mold))) {
        float corr = __expf(mold - mnew);
        lrun *= corr;
        mrun = mnew;
        for (int r = 0; r < 4; ++r) {
          float c = __shfl(corr, lg * 4 + r, 16);
          for (int ht = 0; ht < 8; ++ht) o[ht][r] *= c;
        }
      }
      float mm = mrun;
      float psum = 0.0f;
      for (int n = 0; n < 4; ++n) {
        float p0 = __expf(sacc[n][0] - mm);
        float p1 = __expf(sacc[n][1] - mm);
        float p2 = __expf(sacc[n][2] - mm);
        float p3 = __expf(sacc[n][3] - mm);
        psum += (p0 + p1) + (p2 + p3);
        uint2 pk;
        pk.x = (unsigned)f2bf(p0) | ((unsigned)f2bf(p1) << 16);
        pk.y = (unsigned)f2bf(p2) | ((unsigned)f2bf(p3) << 16);
        *(uint2*)&Plds[w][lr * 64 + ((n * 2 + (lg >> 1)) ^ sw) * 8 + (lg & 1) * 4] = pk;
      }
      psum += __shfl_xor(psum, 16, 64);
      psum += __shfl_xor(psum, 32, 64);
      lrun += psum;

      for (int kk = 0; kk < 2; ++kk) {
        bfx8 pa = *(const bfx8*)&Plds[w][lr * 64 + ((kk * 4 + lg) ^ sw) * 8];
        for (int ht = 0; ht < 8; ++ht) {
          bfx8 vb = *(const bfx8*)&Vlds[cur][(ht * 16 + lr) * 64 + ((kk * 4 + lg) ^ sw) * 8];
          o[ht] = __builtin_amdgcn_mfma_f32_16x16x32_bf16(pa, vb, o[ht], 0, 0, 0);
        }
      }
    }

    for (int r = 0; r < 4; ++r) {
      float inv = 1.0f / __shfl(lrun, lg * 4 + r, 16);
      int qa = wbase + lg * 4 + r;
      u16* dst = ctx + (size_t)(b * S_ + qa) * D_ + h * HD_;
      for (int ht = 0; ht < 8; ++ht)
        dst[ht * 16 + lr] = f2bf(o[ht][r] * inv);
    }
  }
}

extern "C" void kernel_launch(void* const* d_in, const int* in_sizes, int n_in,
                              void* d_out, int out_size, void* d_ws, size_t ws_size,
                              hipStream_t stream) {
  const float* hs     = (const float*)d_in[0];
  const float* w_attn = (const float*)d_in[1];
  const float* b_attn = (const float*)d_in[2];
  const float* w_proj = (const float*)d_in[3];
  const float* b_proj = (const float*)d_in[4];

  u16* Xb     = (u16*)d_ws;            // [4096][2048]
  u16* Wqkvt  = Xb     + 8388608;      // [6144][2048]
  u16* Wprojt = Wqkvt  + 12582912;     // [2048][2048]
  u16* qkvb   = Wprojt + 4194304;      // [4096][6144]
  u16* Vt     = qkvb   + 25165824;     // [32][128][2048]
  u16* ctxb   = Vt     + 8388608;      // [4096][2048]

  cvt_kernel<<<2048, 256, 0, stream>>>(hs, Xb, (B_ * S_ * D_) / 4);
  transpose_cvt64<<<dim3(96, 32), dim3(32, 8), 0, stream>>>(w_attn, Wqkvt, D_, 3 * D_);
  transpose_cvt64<<<dim3(32, 32), dim3(32, 8), 0, stream>>>(w_proj, Wprojt, D_, D_);
  gemm8p<1><<<dim3(24, 16), 512, 0, stream>>>(Xb, Wqkvt, b_attn, qkvb, 4096, 6144, 2048);
  transpose_v64<<<dim3(32, 2, 32), dim3(32, 8), 0, stream>>>(qkvb, Vt);
  attn_kernel<<<dim3(512), 256, 0, stream>>>(qkvb, Vt, ctxb);
  gemm2p<0><<<dim3(8, 32), 512, 0, stream>>>(ctxb, Wprojt, b_proj, d_out, 4096, 2048, 2048);
}